// Round 1
// 712.176 us; speedup vs baseline: 1.1241x; 1.1241x over previous
//
#include <hip/hip_runtime.h>

typedef unsigned short u16;
typedef unsigned int   u32;
typedef __bf16  bf16x8 __attribute__((ext_vector_type(8)));
typedef float   f32x4  __attribute__((ext_vector_type(4)));
typedef u16     u16x8  __attribute__((ext_vector_type(8)));
typedef u16     u16x4  __attribute__((ext_vector_type(4)));

__device__ __forceinline__ float bf2f(u16 v) {
    union { u32 i; float f; } u; u.i = (u32)v << 16; return u.f;
}
__device__ __forceinline__ u16 f2bf(float f) {
    union { float f; u32 i; } u; u.f = f;
    u32 r = (u.i + 0x7FFFu + ((u.i >> 16) & 1u)) >> 16;
    return (u16)r;
}
__device__ __forceinline__ bf16x8 ld8(const u16* p) {
    return __builtin_bit_cast(bf16x8, *(const u16x8*)p);
}
__device__ __forceinline__ void gload16(const void* g, void* l) {
    __builtin_amdgcn_global_load_lds((__attribute__((address_space(1))) void*)g,
                                     (__attribute__((address_space(3))) void*)l, 16, 0, 0);
}

// ---------------------------------------------------------------------------
// dtype detect: low 16 bits of the first 64 words of x. bf16 data -> those are
// N(0,1) samples; fp32 data -> mantissa noise. flag = 1 means fp32 inputs.
// ---------------------------------------------------------------------------
__global__ void detect_kernel(const u16* __restrict__ x, int* __restrict__ flag) {
    if (threadIdx.x == 0 && blockIdx.x == 0) {
        int plausible = 0;
        for (int j = 0; j < 64; j++) {
            float a = fabsf(bf2f(x[2 * j]));
            if (a >= 0.0009765625f && a <= 16.0f) plausible++;
        }
        *flag = (plausible >= 32) ? 0 : 1;
    }
}

// ---------------------------------------------------------------------------
// fp32->bf16 convert (or bf16 passthrough copy), 4 elems/thread, grid-stride.
// ---------------------------------------------------------------------------
__global__ __launch_bounds__(256) void convert_kernel(
    const void* __restrict__ src, u16* __restrict__ dst, int n,
    const int* __restrict__ flag)
{
    int fp32 = *flag;
    int stride = gridDim.x * 256 * 4;
    for (int i = (blockIdx.x * 256 + threadIdx.x) * 4; i < n; i += stride) {
        if (fp32) {
            float4 v = *(const float4*)((const float*)src + i);
            u16x4 o = { f2bf(v.x), f2bf(v.y), f2bf(v.z), f2bf(v.w) };
            *(u16x4*)(dst + i) = o;
        } else {
            *(u16x4*)(dst + i) = *(const u16x4*)((const u16*)src + i);
        }
    }
}

// ---------------------------------------------------------------------------
// rel-pos bias pre-gather: layout [h][tm][tn][c=n%16][r=m%16], n>=196 masked.
// ---------------------------------------------------------------------------
__global__ __launch_bounds__(256) void rpb_prep(const u16* __restrict__ table,
                                                u16* __restrict__ RPB) {
    int idx = blockIdx.x * 256 + threadIdx.x;
    if (idx >= 12 * 13 * 13 * 256) return;
    int r  = idx & 15;
    int c  = (idx >> 4) & 15;
    int q  = idx >> 8;
    int tn = q % 13;
    int q2 = q / 13;
    int tm = q2 % 13;
    int h  = q2 / 13;
    int m = tm * 16 + r, n = tn * 16 + c;
    float val;
    if (n >= 196) {
        val = -30000.0f;                    // mask -> exp underflows to 0
    } else {
        int mc = m > 195 ? 195 : m;         // clamp garbage m-rows
        int i1 = mc / 14, j1 = mc % 14, i2 = n / 14, j2 = n % 14;
        int t = (i1 - i2 + 13) * 27 + (j1 - j2 + 13);
        val = bf2f(table[t * 12 + h]);
    }
    RPB[idx] = f2bf(val);
}

// ---------------------------------------------------------------------------
// bf16 GEMM, 256x256 tile, BK=32, 8 waves (2x4), 4-slot LDS ring staged 3
// tiles ahead via global_load_lds, counted vmcnt(8) (T3+T4), XOR-swizzled LDS
// (T2, conflict-free ds_read_b128; write side via pre-swizzled global src),
// setprio MFMA clusters (T5), bijective XCD block swizzle (T1).
// C[m][n] = sum_k A[m][k]*B[n][k]  (+bias, scale)
// MODE 0: qkv (bias0=q_bias, bias1=v_bias, q-scale 0.125), bf16 store
// MODE 1: proj (bias0=proj_b), window-reverse permuted store, dtype by *flag
// ---------------------------------------------------------------------------
template <int MODE, int NCOLS>
__global__ __launch_bounds__(512, 2) void gemm_kernel(
    const u16* __restrict__ A, const u16* __restrict__ Bw,
    const u16* __restrict__ bias0, const u16* __restrict__ bias1,
    void* __restrict__ Cc, const int* __restrict__ flag)
{
    // 128 KiB: A ring 4 x 16 KiB at byte 0, B ring 4 x 16 KiB at byte 65536.
    __shared__ __align__(16) u16 lds[65536];

    const int tid  = threadIdx.x;
    const int wave = tid >> 6, lane = tid & 63;
    const int quad = lane >> 4, l16 = lane & 15;
    const int wr = wave >> 2, wc = wave & 3;          // 2x4 wave grid

    // ---- bijective XCD swizzle (m204 variant; nwg % 8 != 0 safe) ----
    const int nwg = gridDim.x;
    const int qq = nwg >> 3, rr = nwg & 7;
    const int xcd = blockIdx.x & 7, sub = blockIdx.x >> 3;
    const int wgid = (xcd < rr ? xcd * (qq + 1)
                               : rr * (qq + 1) + (xcd - rr) * qq) + sub;
    const int NT  = NCOLS / 256;
    const int bmt = wgid / NT;
    const int bnt = wgid - bmt * NT;
    const int bm  = bmt * 256, bn = bnt * 256;

    // ---- staging source (pre-swizzled): LDS 16B-unit u holds row u>>2,
    //      logical k-chunk (u&3)^((u>>3)&3). Deposit is linear (wave-uniform
    //      base + lane*16), so the swizzle is applied to the GLOBAL address.
    const int uA0 = tid, uA1 = tid + 512;
    const int rA0 = uA0 >> 2, rA1 = uA1 >> 2;
    const int cA0 = (uA0 & 3) ^ ((uA0 >> 3) & 3);
    const int cA1 = (uA1 & 3) ^ ((uA1 >> 3) & 3);
    const u16* gA0 = A  + (size_t)(bm + rA0) * 768 + cA0 * 8;
    const u16* gA1 = A  + (size_t)(bm + rA1) * 768 + cA1 * 8;
    const u16* gB0 = Bw + (size_t)(bn + rA0) * 768 + cA0 * 8;
    const u16* gB1 = Bw + (size_t)(bn + rA1) * 768 + cA1 * 8;
    char* ldsb = (char*)lds;

    // ---- read-side swizzled fragment offsets (u16 units) ----
    // row = base + frag*16 + l16; (row>>1)&3 == (l16>>1)&3 for all frags.
    const int cp   = quad ^ ((l16 >> 1) & 3);
    const int offA = ((wr * 128 + l16) * 4 + cp) * 8;
    const int offB = ((wc *  64 + l16) * 4 + cp) * 8 + 32768;

#define STAGE_A(tt, ss) do {                                                  \
    char* b_ = ldsb + (ss) * 16384 + wave * 1024;                             \
    gload16(gA0 + (tt) * 32, b_);                                             \
    gload16(gA1 + (tt) * 32, b_ + 8192); } while (0)
#define STAGE_B(tt, ss) do {                                                  \
    char* b_ = ldsb + 65536 + (ss) * 16384 + wave * 1024;                     \
    gload16(gB0 + (tt) * 32, b_);                                             \
    gload16(gB1 + (tt) * 32, b_ + 8192); } while (0)

    // prologue: stage tiles 0,1,2 (12 loads/thread outstanding)
    STAGE_A(0, 0); STAGE_B(0, 0);
    STAGE_A(1, 1); STAGE_B(1, 1);
    STAGE_A(2, 2); STAGE_B(2, 2);

    f32x4 acc[8][4] = {};
    bf16x8 afr[4], bfr[4];

    // Per tile: vmcnt(8) == "everything older than the newest 2 staged tiles
    // is deposited" -> tile t resident. Raw s_barrier (NOT __syncthreads:
    // that would drain vmcnt(0) and kill the pipeline). Empty asm fence stops
    // the compiler hoisting LDS reads / stage issues above the barrier.
#define TILE(t, VMC, DOSTAGE) do {                                            \
    asm volatile("s_waitcnt vmcnt(" #VMC ")" ::: "memory");                   \
    __builtin_amdgcn_s_barrier();                                             \
    asm volatile("" ::: "memory");                                            \
    const u16* sa = lds + ((t) & 3) * 8192;                                   \
    _Pragma("unroll") for (int n = 0; n < 4; n++)                             \
        bfr[n] = ld8(sa + offB + n * 512);                                    \
    _Pragma("unroll") for (int m = 0; m < 4; m++)                             \
        afr[m] = ld8(sa + offA + m * 512);                                    \
    if (DOSTAGE) STAGE_A((t) + 3, ((t) + 3) & 3);                             \
    __builtin_amdgcn_s_setprio(1);                                            \
    _Pragma("unroll") for (int m = 0; m < 4; m++)                             \
      _Pragma("unroll") for (int n = 0; n < 4; n++)                           \
        acc[m][n] = __builtin_amdgcn_mfma_f32_16x16x32_bf16(                  \
            afr[m], bfr[n], acc[m][n], 0, 0, 0);                              \
    __builtin_amdgcn_s_setprio(0);                                            \
    __builtin_amdgcn_s_barrier();                                             \
    _Pragma("unroll") for (int m = 0; m < 4; m++)                             \
        afr[m] = ld8(sa + offA + (m + 4) * 512);                              \
    if (DOSTAGE) STAGE_B((t) + 3, ((t) + 3) & 3);                             \
    __builtin_amdgcn_s_setprio(1);                                            \
    _Pragma("unroll") for (int m = 0; m < 4; m++)                             \
      _Pragma("unroll") for (int n = 0; n < 4; n++)                           \
        acc[m + 4][n] = __builtin_amdgcn_mfma_f32_16x16x32_bf16(              \
            afr[m], bfr[n], acc[m + 4][n], 0, 0, 0);                          \
    __builtin_amdgcn_s_setprio(0);                                            \
} while (0)

    for (int t = 0; t < 21; ++t) TILE(t, 8, 1);
    TILE(21, 8, 0);           // drain: tiles 22,23 still in flight (8 loads)
    TILE(22, 4, 0);           // tile 23 in flight (4 loads)
    TILE(23, 0, 0);

#undef TILE
#undef STAGE_A
#undef STAGE_B

    // ---- epilogue: bias/scale -> bf16 repack via per-wave LDS scratch ----
    __syncthreads();          // ring dead; reuse LDS (vmcnt already 0)

    float bs[4], scl[4];
#pragma unroll
    for (int n = 0; n < 4; n++) {
        int col = bn + wc * 64 + n * 16 + l16;
        if (MODE == 0) {
            if (col < 768)       { bs[n] = bf2f(bias0[col]);        scl[n] = 0.125f; }
            else if (col < 1536) { bs[n] = 0.f;                     scl[n] = 1.f; }
            else                 { bs[n] = bf2f(bias1[col - 1536]); scl[n] = 1.f; }
        } else {
            bs[n] = bf2f(bias0[col]); scl[n] = 1.f;
        }
    }
    const int fp32out = (MODE == 1) ? *flag : 0;
    u16* scratch = &lds[wave * 2048];     // 16 rows x pitch 72 u16 per wave

#pragma unroll
    for (int m = 0; m < 8; m++) {
#pragma unroll
        for (int n = 0; n < 4; n++)
#pragma unroll
            for (int r2 = 0; r2 < 4; r2++)
                scratch[(quad * 4 + r2) * 72 + n * 16 + l16] =
                    f2bf((acc[m][n][r2] + bs[n]) * scl[n]);
        asm volatile("s_waitcnt lgkmcnt(0)" ::: "memory");
#pragma unroll
        for (int j = 0; j < 2; j++) {
            int unit = j * 64 + lane;
            int row = unit >> 3, c8 = unit & 7;
            u16x8 val = *(const u16x8*)&scratch[row * 72 + c8 * 8];
            int gm = bm + wr * 128 + m * 16 + row;
            int gn = bn + wc * 64 + c8 * 8;
            size_t off;
            if (MODE == 0) {
                off = (size_t)gm * NCOLS + gn;
            } else {
                int wwin = gm / 196, tt = gm % 196;
                int b2 = wwin >> 4, wh2 = (wwin >> 2) & 3, ww2 = wwin & 3;
                int ti = tt / 14, tj = tt % 14;
                int g = b2 * 3136 + (wh2 * 14 + ti) * 56 + ww2 * 14 + tj;
                off = (size_t)g * NCOLS + gn;
            }
            if (MODE == 1 && fp32out) {
                float* outf = (float*)Cc;
                float4 lo = { bf2f(val[0]), bf2f(val[1]), bf2f(val[2]), bf2f(val[3]) };
                float4 hi = { bf2f(val[4]), bf2f(val[5]), bf2f(val[6]), bf2f(val[7]) };
                *(float4*)&outf[off]     = lo;
                *(float4*)&outf[off + 4] = hi;
            } else {
                *(u16x8*)&((u16*)Cc)[off] = val;
            }
        }
    }
}

// ---------------------------------------------------------------------------
// Window attention: one block per (window, head). 4 waves, m-tiles strided.
// ---------------------------------------------------------------------------
__global__ __launch_bounds__(256) void attn_kernel(
    const u16* __restrict__ QKV, const u16* __restrict__ RPB, u16* __restrict__ O)
{
    __shared__ __align__(16) u16 k_s[208][72];   // +8 pad for LDS banking
    __shared__ __align__(16) u16 v_t[64][224];   // transposed V: [d][token]
    __shared__ __align__(16) u16 p_s[4][16][40]; // per-wave P chunk (C/D -> A layout)

    const int tid  = threadIdx.x;
    const int wave = tid >> 6, lane = tid & 63;
    const int quad = lane >> 4, l16 = lane & 15;
    const int w = blockIdx.x / 12, h = blockIdx.x % 12;
    const int b = w >> 4, wh = (w >> 2) & 3, ww = w & 3;
    const int gbase = b * 3136 + wh * 14 * 56 + ww * 14;

    for (int c = tid; c < 1568; c += 256) {
        int tok = c >> 3, dg = c & 7;
        int ti = tok / 14, tj = tok % 14;
        size_t grow = (size_t)(gbase + ti * 56 + tj) * 2304 + h * 64 + dg * 8;
        uint4 kk = *(const uint4*)&QKV[grow + 768];
        *(uint4*)&k_s[tok][dg * 8] = kk;
        uint4 vv = *(const uint4*)&QKV[grow + 1536];
        const u16* pv = (const u16*)&vv;
#pragma unroll
        for (int j = 0; j < 8; j++) v_t[dg * 8 + j][tok] = pv[j];
    }
    for (int c = tid; c < 12 * 64; c += 256) k_s[196 + (c >> 6)][c & 63] = 0;
    for (int c = tid; c < 64 * 28; c += 256) v_t[c / 28][196 + c % 28] = 0;
    __syncthreads();

    for (int tm = wave; tm < 13; tm += 4) {
        int tq = tm * 16 + l16; if (tq > 195) tq = 195;
        int qi = tq / 14, qj = tq % 14;
        size_t qoff = (size_t)(gbase + qi * 56 + qj) * 2304 + h * 64 + quad * 8;
        bf16x8 aq0 = ld8(&QKV[qoff]);
        bf16x8 aq1 = ld8(&QKV[qoff + 32]);

        f32x4 sc[13];
#pragma unroll
        for (int tn = 0; tn < 13; tn++) {
            bf16x8 bk0 = ld8(&k_s[tn * 16 + l16][quad * 8]);
            bf16x8 bk1 = ld8(&k_s[tn * 16 + l16][32 + quad * 8]);
            f32x4 z = {};
            z = __builtin_amdgcn_mfma_f32_16x16x32_bf16(aq0, bk0, z, 0, 0, 0);
            sc[tn] = __builtin_amdgcn_mfma_f32_16x16x32_bf16(aq1, bk1, z, 0, 0, 0);
        }
#pragma unroll
        for (int tn = 0; tn < 13; tn++) {
            const u16* rp = &RPB[((((h * 13 + tm) * 13 + tn) * 16 + l16) << 4) + quad * 4];
#pragma unroll
            for (int r = 0; r < 4; r++) sc[tn][r] += bf2f(rp[r]);
        }
        float inv[4];
#pragma unroll
        for (int r = 0; r < 4; r++) {
            float m = -3.0e38f;
#pragma unroll
            for (int tn = 0; tn < 13; tn++) m = fmaxf(m, sc[tn][r]);
#pragma unroll
            for (int d = 1; d < 16; d <<= 1) m = fmaxf(m, __shfl_xor(m, d, 64));
            float s = 0.f;
#pragma unroll
            for (int tn = 0; tn < 13; tn++) {
                float e = __expf(sc[tn][r] - m);
                sc[tn][r] = e; s += e;
            }
#pragma unroll
            for (int d = 1; d < 16; d <<= 1) s += __shfl_xor(s, d, 64);
            inv[r] = 1.f / s;
        }
        f32x4 oc[4] = {};
#pragma unroll
        for (int s7 = 0; s7 < 7; s7++) {
#pragma unroll
            for (int tt = 0; tt < 2; tt++) {
                int tn = 2 * s7 + tt;
#pragma unroll
                for (int r = 0; r < 4; r++) {
                    float pv = (tn < 13) ? sc[tn][r] * inv[r] : 0.f;
                    p_s[wave][quad * 4 + r][tt * 16 + l16] = f2bf(pv);
                }
            }
            __asm__ volatile("s_waitcnt lgkmcnt(0)" ::: "memory");
            bf16x8 ap = ld8(&p_s[wave][l16][quad * 8]);
#pragma unroll
            for (int dt = 0; dt < 4; dt++) {
                bf16x8 bv = ld8(&v_t[dt * 16 + l16][s7 * 32 + quad * 8]);
                oc[dt] = __builtin_amdgcn_mfma_f32_16x16x32_bf16(ap, bv, oc[dt], 0, 0, 0);
            }
        }
#pragma unroll
        for (int dt = 0; dt < 4; dt++)
#pragma unroll
            for (int r = 0; r < 4; r++) {
                int t = tm * 16 + quad * 4 + r;
                if (t < 196)
                    O[(size_t)(w * 196 + t) * 768 + h * 64 + dt * 16 + l16] = f2bf(oc[dt][r]);
            }
    }
}

// ---------------------------------------------------------------------------
extern "C" void kernel_launch(void* const* d_in, const int* in_sizes, int n_in,
                              void* d_out, int out_size, void* d_ws, size_t ws_size,
                              hipStream_t stream) {
    char* ws = (char*)d_ws;
    u16* qkv     = (u16*)(ws);                        // 231,211,008 B
    u16* xbf     = (u16*)(ws + 231211008);            //  77,070,336 B (= attnout)
    u16* attnout = xbf;
    u16* wqkv_bf = (u16*)(ws + 308281344);            //   3,538,944 B
    u16* wproj_bf= (u16*)(ws + 311820288);            //   1,179,648 B
    u16* rpb     = (u16*)(ws + 312999936);            //   1,038,336 B
    u16* qb_bf   = (u16*)(ws + 314038272);
    u16* vb_bf   = (u16*)(ws + 314039808);
    u16* pb_bf   = (u16*)(ws + 314041344);
    u16* tbl_bf  = (u16*)(ws + 314042880);
    int* flag    = (int*)(ws + 314060384);

    detect_kernel<<<1, 64, 0, stream>>>((const u16*)d_in[0], flag);
    convert_kernel<<<4096, 256, 0, stream>>>(d_in[0], xbf,      16 * 3136 * 768, flag);
    convert_kernel<<<1728, 256, 0, stream>>>(d_in[1], wqkv_bf,  2304 * 768,      flag);
    convert_kernel<<< 576, 256, 0, stream>>>(d_in[5], wproj_bf, 768 * 768,       flag);
    convert_kernel<<<   1, 256, 0, stream>>>(d_in[2], qb_bf,    768,             flag);
    convert_kernel<<<   1, 256, 0, stream>>>(d_in[3], vb_bf,    768,             flag);
    convert_kernel<<<   1, 256, 0, stream>>>(d_in[6], pb_bf,    768,             flag);
    convert_kernel<<<   9, 256, 0, stream>>>(d_in[4], tbl_bf,   729 * 12,        flag);

    rpb_prep<<<2028, 256, 0, stream>>>(tbl_bf, rpb);
    // 50176x2304x768: (50176/256)*(2304/256) = 196*9 = 1764 blocks
    gemm_kernel<0, 2304><<<dim3(1764), 512, 0, stream>>>(
        xbf, wqkv_bf, qb_bf, vb_bf, qkv, flag);
    attn_kernel<<<3072, 256, 0, stream>>>(qkv, rpb, attnout);
    // 50176x768x768: 196*3 = 588 blocks
    gemm_kernel<1, 768><<<dim3(588), 512, 0, stream>>>(
        attnout, wproj_bf, pb_bf, pb_bf, d_out, flag);
}